// Round 7
// baseline (3041.584 us; speedup 1.0000x reference)
//
#include <hip/hip_runtime.h>
#include <cstdint>
#include <cstddef>

typedef unsigned short u16;
typedef unsigned int u32;
typedef unsigned long long u64;
typedef __attribute__((ext_vector_type(8))) short short8;   // 8 x bf16
typedef __attribute__((ext_vector_type(4))) float f32x4;

#define MFMA16(a, b, c) __builtin_amdgcn_mfma_f32_16x16x32_bf16((a), (b), (c), 0, 0, 0)
#define SCOPE_AGENT __HIP_MEMORY_SCOPE_AGENT

// B=64, T=512, D=512, H=1024.
// R7: all-L2 steady state. R6 proved flag-gated XCD-local exchange (FETCH 185->148MB)
// but kept agent-scope h stores: each step paid MALL store-acks (~900cy) at the
// post-store __syncthreads, and WRITE_SIZE showed 264MB of h/reset write-through.
// Now: (a) startup FUNCTIONAL visibility test (plain store -> sc0 load, bounded spin,
// agent-voted bg consensus) picks fast/slow mode; (b) fast mode uses PLAIN stores
// (ack at XCD L2) for h + flags, per-wave flag publish after a per-wave vmcnt(0)
// (L2 acks) -> no second __syncthreads; (c) the reduce barrier is raw
// "s_waitcnt lgkmcnt(0); s_barrier" (no vmcnt drain) so the xin prefetch -- issued
// right after the flag publish, a full step before use -- never stalls a barrier.
// Slow mode = all-agent (R6 protocol, proven). Termination of every spin rests on
// demonstrated visibility: fast gate on the startup test + no-WG-migration under
// cooperative launch; slow gate on the R0-proven agent/agent pair.

static __device__ __forceinline__ u16 f2bf_rne(float f) {
  uint32_t u = __float_as_uint(f);
  u += 0x7FFFu + ((u >> 16) & 1u);
  return (u16)(u >> 16);
}
static __device__ __forceinline__ float bf2f(u16 h) {
  return __uint_as_float((uint32_t)h << 16);
}

// sentinel 0xFFFF = bf16 NaN; tanh outputs / remainders are finite -> never 0xFFFF.
static __device__ __forceinline__ u32 stale4(int4 d) {
  u32 s = 0;
#pragma unroll
  for (int j = 0; j < 4; ++j) {
    u32 x = ((u32*)&d)[j];
    s |= (u32)((x >> 16) == 0xFFFFu) | (u32)((x & 0xFFFFu) == 0xFFFFu);
  }
  return s;
}

template <bool FAST>
static __device__ __forceinline__ int4 ldA(const u16* p) {
  int4 r;
  if constexpr (FAST) {
    asm volatile("global_load_dwordx4 %0, %1, off sc0" : "=v"(r) : "v"(p));
  } else {
    u64 a = __hip_atomic_load((const u64*)p, __ATOMIC_RELAXED, SCOPE_AGENT);
    u64 b = __hip_atomic_load(((const u64*)p) + 1, __ATOMIC_RELAXED, SCOPE_AGENT);
    r.x = (int)(u32)a; r.y = (int)(u32)(a >> 32);
    r.z = (int)(u32)b; r.w = (int)(u32)(b >> 32);
  }
  return r;
}
template <bool FAST>
static __device__ __forceinline__ u64 ldF2(const u32* p) {
  u64 r;
  if constexpr (FAST)
    asm volatile("global_load_dwordx2 %0, %1, off sc0" : "=v"(r) : "v"(p));
  else
    r = __hip_atomic_load((const u64*)p, __ATOMIC_RELAXED, SCOPE_AGENT);
  return r;
}
template <bool FAST>
static __device__ __forceinline__ void stH(u16* p, u16 v) {
  if constexpr (FAST)
    *(volatile u16*)p = v;  // plain writeback store: acks at XCD L2
  else
    __hip_atomic_store(p, v, __ATOMIC_RELAXED, SCOPE_AGENT);
}
template <bool FAST>
static __device__ __forceinline__ void stFlag(u32* p, u32 v) {
  if constexpr (FAST)
    *(volatile u32*)p = v;
  else
    __hip_atomic_store(p, v, __ATOMIC_RELAXED, SCOPE_AGENT);
}

// rule #18: drain vmcnt, then hard scheduling fence.
static __device__ __forceinline__ void waitv0() {
  asm volatile("s_waitcnt vmcnt(0)" ::: "memory");
  __builtin_amdgcn_sched_barrier(0);
}
// HK-style barrier: LDS drain only, vmcnt rides through (xin prefetch not stalled).
static __device__ __forceinline__ void bar_lgkm() {
  asm volatile("s_waitcnt lgkmcnt(0)" ::: "memory");
  __builtin_amdgcn_s_barrier();
  __builtin_amdgcn_sched_barrier(0);
}

// ---------------- prep ----------------
__global__ void split_arr(const float* __restrict__ src, u16* __restrict__ hi,
                          u16* __restrict__ lo, int n) {
  int i = blockIdx.x * blockDim.x + threadIdx.x;
  if (i >= n) return;
  float f = src[i];
  u16 h = f2bf_rne(f);
  hi[i] = h;
  lo[i] = f2bf_rne(f - bf2f(h));
}

__global__ void bias_init(const float* __restrict__ a, const float* __restrict__ b,
                          float* __restrict__ o, u32* __restrict__ cnt,
                          u32* __restrict__ tok, u32* __restrict__ vote,
                          u32* __restrict__ flg) {
  int i = blockIdx.x * blockDim.x + threadIdx.x;
  if (i < 1024) o[i] = a[i] + b[i];
  if (i < 1024) __hip_atomic_store(flg + i, 0u, __ATOMIC_RELAXED, SCOPE_AGENT);
  if (i < 256) __hip_atomic_store(tok + i, 0u, __ATOMIC_RELAXED, SCOPE_AGENT);
  if (i < 256) __hip_atomic_store(vote + i, 0u, __ATOMIC_RELAXED, SCOPE_AGENT);
  if (i < 8) __hip_atomic_store(cnt + i * 64, 0u, __ATOMIC_RELAXED, SCOPE_AGENT);
}

// ---------------- phase 1: xin = x @ W_in^T + bsum -> d_out (unchanged, proven) ----
__global__ __launch_bounds__(256) void xin_gemm(
    const float* __restrict__ x, const u16* __restrict__ Bh, const u16* __restrict__ Bl,
    const float* __restrict__ bsum, float* __restrict__ out) {
  __shared__ u16 Ahi[64 * 40], Alo[64 * 40], Bhi[64 * 40], Blo[64 * 40];
  const int mb = blockIdx.y * 64, nb = blockIdx.x * 64;
  const int tid = threadIdx.x, wave = tid >> 6, lane = tid & 63;
  const int mn = lane & 15, q = lane >> 4;
  const int srow = tid >> 2, scg = tid & 3;

  f32x4 acc[4] = {};
  for (int kb = 0; kb < 512; kb += 32) {
    const float* ap = x + (size_t)(mb + srow) * 512 + kb + scg * 8;
    float4 a0 = *(const float4*)ap;
    float4 a1 = *(const float4*)(ap + 4);
    float av[8] = {a0.x, a0.y, a0.z, a0.w, a1.x, a1.y, a1.z, a1.w};
    short8 vh, vl;
#pragma unroll
    for (int j = 0; j < 8; ++j) {
      u16 h = f2bf_rne(av[j]);
      vh[j] = (short)h;
      vl[j] = (short)f2bf_rne(av[j] - bf2f(h));
    }
    short8 wh = *(const short8*)(Bh + (size_t)(nb + srow) * 512 + kb + scg * 8);
    short8 wl = *(const short8*)(Bl + (size_t)(nb + srow) * 512 + kb + scg * 8);

    __syncthreads();
    *(short8*)&Ahi[srow * 40 + scg * 8] = vh;
    *(short8*)&Alo[srow * 40 + scg * 8] = vl;
    *(short8*)&Bhi[srow * 40 + scg * 8] = wh;
    *(short8*)&Blo[srow * 40 + scg * 8] = wl;
    __syncthreads();

    short8 ah = *(const short8*)&Ahi[(wave * 16 + mn) * 40 + q * 8];
    short8 al = *(const short8*)&Alo[(wave * 16 + mn) * 40 + q * 8];
#pragma unroll
    for (int nt = 0; nt < 4; ++nt) {
      short8 bh8 = *(const short8*)&Bhi[(nt * 16 + mn) * 40 + q * 8];
      short8 bl8 = *(const short8*)&Blo[(nt * 16 + mn) * 40 + q * 8];
      acc[nt] = MFMA16(ah, bh8, acc[nt]);
      acc[nt] = MFMA16(al, bh8, acc[nt]);
      acc[nt] = MFMA16(ah, bl8, acc[nt]);
    }
  }
#pragma unroll
  for (int nt = 0; nt < 4; ++nt)
#pragma unroll
    for (int r = 0; r < 4; ++r) {
      int row = mb + wave * 16 + q * 4 + r;
      int col = nb + nt * 16 + mn;
      out[(size_t)row * 1024 + col] = acc[nt][r] + bsum[col];
    }
}

// ---------------- phase 2 step loop ----------------
// Per step t: [poll 128 per-wave flags (512B) until all >= t] [8 A loads + waitv0]
// [sentinel check (backstop; flag publish order makes retries ~impossible)]
// [reset buf[(t+4)&7]] [8x2x2 MFMA] [red write] [lgkm-only barrier] [cross-wave sum]
// [tanh] [h stores -> per-wave vmcnt(0) (L2 acks) -> lane0 flag := t+1] [io store]
// [xin(t+1) prefetch, drained by next gate]. Same-address reset(t)->data(t+3)
// ordered by step-t's pre-flag vmcnt(0). Skew across WGs <= 1 step.
template <bool FAST>
static __device__ __forceinline__ void run_steps(
    u16* hhi, u16* hlo, float* __restrict__ io, const u16* Whi, const u16* Wlo,
    float* red, const u32* fp, u32* myflag, int b0, int c0, int wave, int mn,
    int q, int om, int on, int lane) {
  const int kbase = wave * 256;
  u16* aplane = (mn < 8) ? hhi : hlo;  // A rows 0-7 = hi, 8-15 = lo
  const size_t abase = (size_t)(b0 + (mn & 7)) * 1024 + kbase + q * 8;
  const size_t iobase = (size_t)(b0 + om) * 512 * 1024 + (c0 + on);
  const size_t hword = (size_t)(b0 + om) * 1024 + (c0 + on);

  // W frags hoisted (compiler may keep in VGPR or re-read LDS; both fine)
  short8 bhf[8][2], blf[8][2];
#pragma unroll
  for (int kt = 0; kt < 8; ++kt) {
    const int k = kbase + kt * 32 + q * 8;
#pragma unroll
    for (int nt = 0; nt < 2; ++nt) {
      bhf[kt][nt] = *(const short8*)&Whi[(nt * 16 + mn) * 1032 + k];
      blf[kt][nt] = *(const short8*)&Wlo[(nt * 16 + mn) * 1032 + k];
    }
  }

  float xv = io[iobase];  // xin(0)
  {                       // t = 0: h0 == 0 -> h1 = tanh(xin0), no GEMM
    float o = tanhf(xv);
    u16 hh = f2bf_rne(o);
    stH<FAST>(hhi + (1u << 16) + hword, hh);
    stH<FAST>(hlo + (1u << 16) + hword, f2bf_rne(o - bf2f(hh)));
    waitv0();                                   // per-wave: h(1) acked at L2/MALL
    if (lane == 0) stFlag<FAST>(myflag, 1u);    // publish AFTER data completion
    io[iobase] = o;
    xv = io[iobase + 1024];                     // xin(1) prefetch
  }

  for (int t = 1; t < 512; ++t) {
    const u32 ut = (u32)t;
    // ---- flag gate: all 32 WGs x 4 waves published h(t). First round's waitv0
    // also drains our own prev-step io store + xin prefetch. ----
    for (;;) {
      u64 f2 = ldF2<FAST>(fp);
      waitv0();
      if (__ballot(((u32)f2 >= ut) & ((u32)(f2 >> 32) >= ut)) == ~0ull) break;
    }

    // ---- A-slice load; sentinel backstop (flag order makes retries ~never) ----
    const u16* pA = aplane + ((size_t)(t & 7) << 16) + abase;
    int4 v[8];
#pragma unroll
    for (int kt = 0; kt < 8; ++kt) v[kt] = ldA<FAST>(pA + kt * 32);
    waitv0();
    u32 sm = 0;
#pragma unroll
    for (int kt = 0; kt < 8; ++kt) sm |= stale4(v[kt]) << kt;
    while (__builtin_expect(sm != 0, 0)) {
#pragma unroll
      for (int kt = 0; kt < 8; ++kt)
        if (sm & (1u << kt)) v[kt] = ldA<FAST>(pA + kt * 32);
      waitv0();
      sm = 0;
#pragma unroll
      for (int kt = 0; kt < 8; ++kt) sm |= stale4(v[kt]) << kt;
    }

    if (t < 508) {  // reset buf[(t+4)&7]: holds h(t-4), consumed >= 3 steps ago
      const size_t roff = ((size_t)((t + 4) & 7) << 16) + hword;
      stH<FAST>(hhi + roff, 0xFFFFu);
      stH<FAST>(hlo + roff, 0xFFFFu);
    }

    f32x4 acc[2] = {};
#pragma unroll
    for (int kt = 0; kt < 8; ++kt) {
      short8 a = *(short8*)&v[kt];
#pragma unroll
      for (int nt = 0; nt < 2; ++nt) {
        acc[nt] = MFMA16(a, bhf[kt][nt], acc[nt]);  // rows 0-7: hi*Whi, 8-15: lo*Whi
        acc[nt] = MFMA16(a, blf[kt][nt], acc[nt]);  // rows 0-7: hi*Wlo, 8-15: lo*Wlo
      }
    }

    float* rp = red + (t & 1) * 2112;
#pragma unroll
    for (int nt = 0; nt < 2; ++nt)
#pragma unroll
      for (int r = 0; r < 4; ++r)
        rp[wave * 528 + (q * 4 + r) * 33 + nt * 16 + mn] = acc[nt][r];
    bar_lgkm();  // LDS drain only; outstanding VMEM rides through

    float s = 0.f;
#pragma unroll
    for (int w = 0; w < 4; ++w)
      s += rp[w * 528 + om * 33 + on] + rp[w * 528 + (om + 8) * 33 + on];
    float o = tanhf(s + xv);

    if (t < 511) {
      u16 hh = f2bf_rne(o);
      const size_t doff = ((size_t)((t + 1) & 7) << 16) + hword;
      stH<FAST>(hhi + doff, hh);
      stH<FAST>(hlo + doff, f2bf_rne(o - bf2f(hh)));
      waitv0();  // per-wave: resets + h(t+1) acked (L2 in fast mode) before flag
      if (lane == 0) stFlag<FAST>(myflag, ut + 1);
    }
    io[iobase + (size_t)t * 1024] = o;
    if (t < 511) xv = io[iobase + (size_t)(t + 1) * 1024];  // drained at next gate
  }
}

// ---------------- phase 2 kernel ----------------
__global__ __launch_bounds__(256, 1) void rnn_steps(
    const u16* __restrict__ Wh, const u16* __restrict__ Wl, u16* hhi, u16* hlo,
    u32* cnt, u32* tok, u32* vote, u32* flg, float* __restrict__ io) {
  extern __shared__ __align__(16) char smem[];
  u16* Whi = (u16*)smem;                 // [32][1032]  66048 B
  u16* Wlo = (u16*)(smem + 66048);       // [32][1032]  66048 B
  float* red = (float*)(smem + 132096);  // [2][4][16][33] 16896 B

  const int tid = threadIdx.x, wave = tid >> 6, lane = tid & 63;
  const int mn = lane & 15, q = lane >> 4;
  const int wgid = blockIdx.x;
  const int bg = wgid & 7, cg = wgid >> 3;
  const int c0 = cg * 32, b0 = bg * 8;
  u32* mycnt = cnt + bg * 64;

  // persistent W tile: 32 cols x 1024, hi+lo
  for (int it = tid; it < 32 * 128; it += 256) {
    int r = it >> 7, c = it & 127;
    *(short8*)&Whi[r * 1032 + c * 8] = *(const short8*)(Wh + (size_t)(c0 + r) * 1024 + c * 8);
    *(short8*)&Wlo[r * 1032 + c * 8] = *(const short8*)(Wl + (size_t)(c0 + r) * 1024 + c * 8);
  }

  // output ownership: 256 threads -> 8 batches x 32 cols, 1 col/thread
  const int om = tid >> 5, on = tid & 31;
  const size_t hword = (size_t)(b0 + om) * 1024 + (c0 + on);

  // sentinel-prefill my word in ALL 8 buffers (agent scope: MALL-visible on any path)
#pragma unroll
  for (int bb = 0; bb < 8; ++bb) {
    __hip_atomic_store(hhi + ((size_t)bb << 16) + hword, (u16)0xFFFFu, __ATOMIC_RELAXED,
                       SCOPE_AGENT);
    __hip_atomic_store(hlo + ((size_t)bb << 16) + hword, (u16)0xFFFFu, __ATOMIC_RELAXED,
                       SCOPE_AGENT);
  }
  // functional visibility test, phase 1: plain-store my token
  if (tid == 0) *(volatile u32*)(tok + wgid) = (u32)(wgid + 1);
  asm volatile("s_waitcnt vmcnt(0)" ::: "memory");
  __syncthreads();
  if (tid == 0) {  // counter barrier #1: all tokens stored (in some L2)
    __hip_atomic_fetch_add(mycnt, 1u, __ATOMIC_RELAXED, SCOPE_AGENT);
    while (__hip_atomic_load(mycnt, __ATOMIC_RELAXED, SCOPE_AGENT) < 32u)
      __builtin_amdgcn_s_sleep(1);
  }
  __syncthreads();

  // phase 2: wave0 sc0-reads all 32 tokens of this bg; bounded spin -> ok/fail
  int okflag = 1;
  if (wave == 0) {
    int rounds = 0;
    for (;;) {
      u32 tv = 0;
      if (lane < 32) {
        const u32* tp = tok + lane * 8 + bg;  // wgid of bg's WGs = cg*8+bg
        asm volatile("global_load_dword %0, %1, off sc0" : "=v"(tv) : "v"(tp));
      }
      waitv0();
      if (__ballot(lane >= 32 || tv == (u32)(lane * 8 + bg + 1)) == ~0ull) break;
      if (++rounds >= 4096) { okflag = 2; break; }  // bounded: no hang on bad topology
    }
  }
  if (tid == 0) *(int*)red = okflag;
  __syncthreads();
  int myvote = *(int*)red;
  __syncthreads();
  if (tid == 0)
    __hip_atomic_store(vote + wgid, (u32)myvote, __ATOMIC_RELAXED, SCOPE_AGENT);
  asm volatile("s_waitcnt vmcnt(0)" ::: "memory");
  __syncthreads();
  if (tid == 0) {  // counter barrier #2: all votes published
    __hip_atomic_fetch_add(mycnt, 1u, __ATOMIC_RELAXED, SCOPE_AGENT);
    while (__hip_atomic_load(mycnt, __ATOMIC_RELAXED, SCOPE_AGENT) < 64u)
      __builtin_amdgcn_s_sleep(1);
  }
  __syncthreads();
  // consensus: fast iff ALL 32 WGs of this bg demonstrated visibility
  u32 vv = 1;
  if (lane < 32)
    vv = __hip_atomic_load(vote + lane * 8 + bg, __ATOMIC_RELAXED, SCOPE_AGENT);
  const bool fast = (__ballot(vv == 1u) == ~0ull);

  const u32* fp = flg + bg * 128 + lane * 2;     // poll base: 128 per-wave flags
  u32* myflag = flg + bg * 128 + cg * 4 + wave;  // my per-wave flag

  if (fast)
    run_steps<true>(hhi, hlo, io, Whi, Wlo, red, fp, myflag, b0, c0, wave, mn, q, om, on, lane);
  else
    run_steps<false>(hhi, hlo, io, Whi, Wlo, red, fp, myflag, b0, c0, wave, mn, q, om, on, lane);
}

// ---------------- host ----------------
extern "C" void kernel_launch(void* const* d_in, const int* in_sizes, int n_in, void* d_out,
                              int out_size, void* d_ws, size_t ws_size, hipStream_t stream) {
  (void)in_sizes; (void)n_in; (void)out_size; (void)ws_size;
  const float* x    = (const float*)d_in[0];
  const float* W_in = (const float*)d_in[1];
  const float* b_in = (const float*)d_in[2];
  const float* W_hh = (const float*)d_in[3];
  const float* bias = (const float*)d_in[4];
  float* out = (float*)d_out;
  char* ws = (char*)d_ws;

  u16* win_hi = (u16*)(ws);                     // 1 MB, dead after xin_gemm
  u16* win_lo = (u16*)(ws + (1u << 20));        // 1 MB, dead after xin_gemm
  u16* whh_hi = (u16*)(ws + (2u << 20));        // 2 MB
  u16* whh_lo = (u16*)(ws + (4u << 20));        // 2 MB
  float* bsum = (float*)(ws + (6u << 20));      // 4 KB
  u16* hhi    = (u16*)(ws);                     // aliases win_hi: 8 bufs x 64x1024 u16
  u16* hlo    = (u16*)(ws + (1u << 20));        // aliases win_lo
  u32* cnt    = (u32*)(ws + (6u << 20) + 65536);           // 8 x 256B counters
  u32* tok    = (u32*)(ws + (6u << 20) + 65536 + 4096);    // 256 u32 tokens
  u32* vote   = (u32*)(ws + (6u << 20) + 65536 + 8192);    // 256 u32 votes
  u32* flg    = (u32*)(ws + (6u << 20) + 65536 + 12288);   // flags[8][128], 512B/bg

  split_arr<<<dim3(524288 / 256), dim3(256), 0, stream>>>(W_in, win_hi, win_lo, 524288);
  split_arr<<<dim3(1048576 / 256), dim3(256), 0, stream>>>(W_hh, whh_hi, whh_lo, 1048576);
  bias_init<<<dim3(8), dim3(256), 0, stream>>>(b_in, bias, bsum, cnt, tok, vote, flg);

  xin_gemm<<<dim3(16, 512), dim3(256), 0, stream>>>(x, win_hi, win_lo, bsum, out);

  static const unsigned kSmem = 148992;  // 2*66048 + 16896
  (void)hipFuncSetAttribute((const void*)rnn_steps, hipFuncAttributeMaxDynamicSharedMemorySize,
                            (int)kSmem);
  void* args[9];
  args[0] = (void*)&whh_hi;
  args[1] = (void*)&whh_lo;
  args[2] = (void*)&hhi;
  args[3] = (void*)&hlo;
  args[4] = (void*)&cnt;
  args[5] = (void*)&tok;
  args[6] = (void*)&vote;
  args[7] = (void*)&flg;
  args[8] = (void*)&out;
  (void)hipLaunchCooperativeKernel((const void*)rnn_steps, dim3(256), dim3(256, 1, 1), args,
                                   kSmem, stream);
}